// Round 5
// baseline (378.356 us; speedup 1.0000x reference)
//
#include <hip/hip_runtime.h>
#include <hip/hip_bf16.h>

#define DEVI __device__ __forceinline__

typedef __attribute__((ext_vector_type(8))) short bf16x8;
typedef __attribute__((ext_vector_type(4))) float f32x4;
typedef unsigned short u16;
typedef unsigned long long u64;

// ---------------- helpers ----------------

DEVI void async16(const void* g, const void* l) {
  __builtin_amdgcn_global_load_lds(
      (const __attribute__((address_space(1))) unsigned int*)g,
      (__attribute__((address_space(3))) unsigned int*)l, 16, 0, 0);
}

DEVI u16 f2bf(float x) {  // RNE f32->bf16 (finite inputs only)
  unsigned int u = __float_as_uint(x);
  return (u16)((u + 0x7fffu + ((u >> 16) & 1u)) >> 16);
}

DEVI float fast_exp2(float x) {
#if __has_builtin(__builtin_amdgcn_exp2f)
  return __builtin_amdgcn_exp2f(x);  // raw v_exp_f32, no libm wrapper
#else
  return exp2f(x);
#endif
}

// ---------------- fused prep kernel ----------------
// blocks [0,8192)       cast ctx -> Xc
// blocks [8192,16384)   cast val -> Xv
// blocks [16384,17408)  cast Wo  -> WoB
// blocks [17408,18176)  LDS-tiled transpose Wq/Wk/Wv -> Wqt/Wkt/Wvt (bf16)
// blocks [18176,34560)  mask bit-pack (TRANSPOSED: mbits[word][row])
// blocks [34560,34568)  bias concat bq|bk -> bqk

__global__ __launch_bounds__(256) void prep_kernel(
    const float* __restrict__ ctx, const float* __restrict__ val, const int* __restrict__ msk,
    const float* __restrict__ Wq, const float* __restrict__ Wk, const float* __restrict__ Wv,
    const float* __restrict__ Wo, const float* __restrict__ bq, const float* __restrict__ bk,
    u16* __restrict__ Xc, u16* __restrict__ Xv, u16* __restrict__ Wqt, u16* __restrict__ Wkt,
    u16* __restrict__ Wvt, u16* __restrict__ WoB, u64* __restrict__ mbits, float* __restrict__ bqk) {
  __shared__ float tile[64 * 69];
  const int blk = blockIdx.x, tid = threadIdx.x;
  if (blk < 16384) {
    const float* src = (blk < 8192) ? ctx : val;
    u16* dst = (blk < 8192) ? Xc : Xv;
    int i = (blk & 8191) * 256 + tid;
    float4 v = ((const float4*)src)[i];
    ushort4 o;
    o.x = f2bf(v.x); o.y = f2bf(v.y); o.z = f2bf(v.z); o.w = f2bf(v.w);
    ((ushort4*)dst)[i] = o;
  } else if (blk < 17408) {
    int i = (blk - 16384) * 256 + tid;
    float4 v = ((const float4*)Wo)[i];
    ushort4 o;
    o.x = f2bf(v.x); o.y = f2bf(v.y); o.z = f2bf(v.z); o.w = f2bf(v.w);
    ((ushort4*)WoB)[i] = o;
  } else if (blk < 18176) {
    // W [H=16][1024 d][64 k] -> Wt [h*64+k][1024 d]; 256 blocks per matrix
    int t = blk - 17408;
    int mat = t >> 8, r = t & 255, h = r >> 4, d0 = (r & 15) * 64;
    const float* Ws = (mat == 0) ? Wq : (mat == 1) ? Wk : Wv;
    u16* Wd = (mat == 0) ? Wqt : (mat == 1) ? Wkt : Wvt;
    const int dg = tid & 15, rg = tid >> 4;
#pragma unroll
    for (int i = 0; i < 4; i++) {
      int dr = rg + i * 16;
      float4 v = *(const float4*)&Ws[((size_t)(h * 1024 + d0 + dr)) * 64 + dg * 4];
      tile[dr * 69 + dg * 4 + 0] = v.x;
      tile[dr * 69 + dg * 4 + 1] = v.y;
      tile[dr * 69 + dg * 4 + 2] = v.z;
      tile[dr * 69 + dg * 4 + 3] = v.w;
    }
    __syncthreads();
#pragma unroll
    for (int i = 0; i < 4; i++) {
      int k = rg + i * 16;
      ushort4 o;
      o.x = f2bf(tile[(dg * 4 + 0) * 69 + k]);
      o.y = f2bf(tile[(dg * 4 + 1) * 69 + k]);
      o.z = f2bf(tile[(dg * 4 + 2) * 69 + k]);
      o.w = f2bf(tile[(dg * 4 + 3) * 69 + k]);
      *(ushort4*)&Wd[(size_t)(h * 64 + k) * 1024 + d0 + dg * 4] = o;
    }
  } else if (blk < 34560) {
    int gid = (blk - 18176) * 256 + tid;  // gid = row*2048 + col over [S][S]
    u64 bal = __ballot(msk[gid] == 1);
    if ((tid & 63) == 0) mbits[(size_t)((gid >> 6) & 31) * 2048 + (gid >> 11)] = bal;
  } else {
    int i = (blk - 34560) * 256 + tid;  // 0..2047
    bqk[i] = (i < 1024) ? bq[i] : bk[i - 1024];
  }
}

// ---------------- fused QKV projection GEMM ----------------
// grid (64, 24). y<16: QK half — C_qk[M][2048] bf16 = Xc*Wqkt^T (+bqk), Q cols scaled.
// y>=16: V half — Vtg[bh][dk][S] bf16 transposed = Xv*Wvt^T (+bv).
// 128x128 tile, BK=32, 4 waves, global_load_lds staging (m97 structure).

__global__ __launch_bounds__(256) void qkv_gemm(const u16* __restrict__ Xc, const u16* __restrict__ Xv,
                                                const u16* __restrict__ Wqkt, const u16* __restrict__ Wvt,
                                                const float* __restrict__ bqk, const float* __restrict__ bvv,
                                                u16* __restrict__ QKb, u16* __restrict__ Vtg, float qscale) {
  __shared__ __align__(16) u16 As[128 * 32];
  __shared__ __align__(16) u16 Bs[128 * 32];
  const int tid = threadIdx.x;
  const int w = tid >> 6, lane = tid & 63, quad = lane >> 4, lc = lane & 15;
  const int K = 1024;
  const bool isV = blockIdx.y >= 16;
  const int m0 = blockIdx.x * 128;
  const int n0 = (isV ? (blockIdx.y - 16) : blockIdx.y) * 128;
  const u16* A  = isV ? Xv : Xc;
  const u16* Bt = isV ? Wvt : Wqkt;
  const float* bias = isV ? bvv : bqk;
  const int wrow = (w >> 1) * 64, wcol = (w & 1) * 64;
  const int srow = tid >> 2, sc = tid & 3;
  const u16* Ag = A + (size_t)(m0 + srow) * K + sc * 8;
  const u16* Bg = Bt + (size_t)(n0 + srow) * K + sc * 8;
  u16* Asw = As + w * 512;
  u16* Bsw = Bs + w * 512;

  f32x4 acc[4][4] = {};
  for (int k0 = 0; k0 < K; k0 += 32) {
    async16(Ag + k0, Asw);
    async16(Ag + k0 + (size_t)64 * K, Asw + 2048);
    async16(Bg + k0, Bsw);
    async16(Bg + k0 + (size_t)64 * K, Bsw + 2048);
    __syncthreads();
    bf16x8 af[4], bfr[4];
#pragma unroll
    for (int rt = 0; rt < 4; rt++) af[rt] = *(const bf16x8*)&As[(wrow + rt * 16 + lc) * 32 + quad * 8];
#pragma unroll
    for (int ct = 0; ct < 4; ct++) bfr[ct] = *(const bf16x8*)&Bs[(wcol + ct * 16 + lc) * 32 + quad * 8];
#pragma unroll
    for (int rt = 0; rt < 4; rt++)
#pragma unroll
      for (int ct = 0; ct < 4; ct++)
        acc[rt][ct] = __builtin_amdgcn_mfma_f32_16x16x32_bf16(af[rt], bfr[ct], acc[rt][ct], 0, 0, 0);
    __syncthreads();
  }
#pragma unroll
  for (int ct = 0; ct < 4; ct++) {
    int col = n0 + wcol + ct * 16 + lc;
    float bv = bias[col];
    float os = (!isV && col < 1024) ? qscale : 1.0f;
#pragma unroll
    for (int rt = 0; rt < 4; rt++) {
      if (isV) {
        int trow = m0 + wrow + rt * 16 + quad * 4;  // 4-aligned, never crosses 2048
        ushort4 pk;
        pk.x = f2bf(acc[rt][ct][0] + bv);
        pk.y = f2bf(acc[rt][ct][1] + bv);
        pk.z = f2bf(acc[rt][ct][2] + bv);
        pk.w = f2bf(acc[rt][ct][3] + bv);
        size_t off = ((size_t)(trow >> 11) * 1024 + col) * 2048 + (trow & 2047);
        *(ushort4*)(Vtg + off) = pk;
      } else {
#pragma unroll
        for (int r = 0; r < 4; r++) {
          int row = m0 + wrow + rt * 16 + quad * 4 + r;
          QKb[(size_t)row * 2048 + col] = f2bf((acc[rt][ct][r] + bv) * os);
        }
      }
    }
  }
}

// ---------------- flash attention v5 (S^T form) ----------------
// grid (S/128 = 16, B*H = 64). Block 256 = 4 waves, each wave 32 q-rows (2 strips).
// Computes S^T = K·Q^T so the C-layout puts q in lanes and CONSECUTIVE t in regs:
// P packs to bf16 via v_perm and stores as ds_write_b64 (vs 32 scalar u16 writes).
// QK: bf16 [B*S][2048] (cols 0-1023 Q pre-scaled by 0.125*log2e, 1024-2047 K).
// Vt: bf16 [bh][dk][S]. mbits transposed [word][row]. No max-subtraction.
// LDS 40 KB: Ks dbuf 16K (Q pre-staged here) + Vs dbuf 16K + Ps 8K.

__global__ __launch_bounds__(256, 4) void attn_kernel(const u16* __restrict__ QK, const u16* __restrict__ Vt,
                                                      const u64* __restrict__ mbits, u16* __restrict__ AO) {
  __shared__ __align__(16) u16 Ks[2][4096];
  __shared__ __align__(16) u16 Vs[2][4096];
  __shared__ __align__(16) u16 Ps[4096];  // per-wave 16x64 P tile (strip-sequential)
  const int S = 2048, D = 1024, QS = 2048;
  const int tid = threadIdx.x, w = tid >> 6, lane = tid & 63, quad = lane >> 4, lc = lane & 15;
  const int q0 = blockIdx.x * 128;
  const int b = blockIdx.y >> 4, h = blockIdx.y & 15;
  const size_t baseq = (size_t)b * S * QS + (size_t)h * 64;
  const size_t vbase = (size_t)blockIdx.y * 64 * S;
  const int sr = lane >> 3, gch = (lane & 7) ^ sr, lx = lc & 7;
  u16* Ksq = (u16*)Ks;  // 16 KB = 128 rows x 64 — Q pre-stage area

  // stage Q (wave w: rows q0+w*32 .. +31) into Ks region, chunk-XOR swizzled
#pragma unroll
  for (int i = 0; i < 4; i++) {
    const u16* g = QK + baseq + (size_t)(q0 + w * 32 + i * 8 + sr) * QS + gch * 8;
    async16(g, Ksq + w * 2048 + i * 512);
  }
  const u16* Kg0 = QK + baseq + 1024 + (size_t)(w * 16 + sr) * QS + gch * 8;
  const u16* Vg0 = Vt + vbase + (size_t)(w * 16 + sr) * S + gch * 8;
  __syncthreads();  // Q staged

  // Q fragments -> registers: aq[strip][ks] (used as the MFMA B operand;
  // A- and B-fragment per-lane layouts are identical for 16x16x32)
  bf16x8 aq[2][2];
#pragma unroll
  for (int s = 0; s < 2; s++)
#pragma unroll
    for (int ks = 0; ks < 2; ks++)
      aq[s][ks] = *(const bf16x8*)&Ksq[w * 2048 + (s * 16 + lc) * 64 + (((ks * 4 + quad) ^ lx) << 3)];
  __syncthreads();  // all aq reads done before K staging overwrites region

  // prefetch tile 0
  async16(Kg0, Ks[0] + w * 1024);
  async16(Kg0 + (size_t)8 * QS, Ks[0] + w * 1024 + 512);
  async16(Vg0, Vs[0] + w * 1024);
  async16(Vg0 + (size_t)8 * S, Vs[0] + w * 1024 + 512);

  const u64* mrow = mbits + (size_t)(q0 + w * 32 + lc);

  bf16x8 ones;
#pragma unroll
  for (int j = 0; j < 8; j++) ones[j] = (short)0x3F80;  // bf16 1.0

  f32x4 acco[2][4] = {};
  f32x4 accl[2] = {};

  for (int t0 = 0; t0 < S; t0 += 64) {
    const int cur = (t0 >> 6) & 1;
    __syncthreads();  // buf[cur] staged; all waves done with buf[cur^1]
    if (t0 + 64 < S) {
      const u16* Kg = Kg0 + (size_t)(t0 + 64) * QS;
      const u16* Vg = Vg0 + (t0 + 64);
      async16(Kg, Ks[cur ^ 1] + w * 1024);
      async16(Kg + (size_t)8 * QS, Ks[cur ^ 1] + w * 1024 + 512);
      async16(Vg, Vs[cur ^ 1] + w * 1024);
      async16(Vg + (size_t)8 * S, Vs[cur ^ 1] + w * 1024 + 512);
    }
    // mask words: one coalesced u64 per strip (lane lc = q-row)
    u64 mword0 = mrow[(size_t)(t0 >> 6) * 2048];
    u64 mword1 = mrow[(size_t)(t0 >> 6) * 2048 + 16];

    // S^T = K·Q^T: lane holds q=lc, t = tt*16 + quad*4 + r (consecutive r!)
    f32x4 sacc[2][4] = {};
#pragma unroll
    for (int ks = 0; ks < 2; ks++)
#pragma unroll
      for (int tt = 0; tt < 4; tt++) {
        bf16x8 kf = *(const bf16x8*)&Ks[cur][(tt * 16 + lc) * 64 + (((ks * 4 + quad) ^ lx) << 3)];
        sacc[0][tt] = __builtin_amdgcn_mfma_f32_16x16x32_bf16(kf, aq[0][ks], sacc[0][tt], 0, 0, 0);
        sacc[1][tt] = __builtin_amdgcn_mfma_f32_16x16x32_bf16(kf, aq[1][ks], sacc[1][tt], 0, 0, 0);
      }

    // per strip: exp2 -> pack bf16 pairs (v_perm) -> ds_write_b64 -> PV
#pragma unroll
    for (int s = 0; s < 2; s++) {
      u64 wq = (s ? mword1 : mword0) >> (quad * 4);
      unsigned mlo = (unsigned)wq, mhi = (unsigned)(wq >> 32);
#pragma unroll
      for (int tt = 0; tt < 4; tt++) {
        unsigned bits = ((tt & 2) ? mhi : mlo) >> ((tt & 1) * 16);
        float pa0 = fast_exp2((bits & 1u) ? -1e4f : sacc[s][tt][0]);
        float pa1 = fast_exp2((bits & 2u) ? -1e4f : sacc[s][tt][1]);
        float pa2 = fast_exp2((bits & 4u) ? -1e4f : sacc[s][tt][2]);
        float pa3 = fast_exp2((bits & 8u) ? -1e4f : sacc[s][tt][3]);
        uint2 pk;
        pk.x = __builtin_amdgcn_perm(__float_as_uint(pa1), __float_as_uint(pa0), 0x07060302);
        pk.y = __builtin_amdgcn_perm(__float_as_uint(pa3), __float_as_uint(pa2), 0x07060302);
        const int c = tt * 2 + (quad >> 1);  // unswizzled 8-elem chunk of t-run
        *(uint2*)&Ps[w * 1024 + lc * 64 + ((c ^ lx) << 3) + (quad & 1) * 4] = pk;
      }
#pragma unroll
      for (int ks = 0; ks < 2; ks++) {
        bf16x8 ap = *(const bf16x8*)&Ps[w * 1024 + lc * 64 + (((ks * 4 + quad) ^ lx) << 3)];
#pragma unroll
        for (int ct = 0; ct < 4; ct++) {
          bf16x8 bv = *(const bf16x8*)&Vs[cur][(ct * 16 + lc) * 64 + (((ks * 4 + quad) ^ lx) << 3)];
          acco[s][ct] = __builtin_amdgcn_mfma_f32_16x16x32_bf16(ap, bv, acco[s][ct], 0, 0, 0);
        }
        accl[s] = __builtin_amdgcn_mfma_f32_16x16x32_bf16(ap, ones, accl[s], 0, 0, 0);
      }
    }
  }

#pragma unroll
  for (int s = 0; s < 2; s++)
#pragma unroll
    for (int r = 0; r < 4; r++) {
      float inv = 1.0f / accl[s][r];
      size_t row = (size_t)b * S + q0 + w * 32 + s * 16 + quad * 4 + r;
#pragma unroll
      for (int ct = 0; ct < 4; ct++)
        AO[row * D + h * 64 + ct * 16 + lc] = f2bf(acco[s][ct][r] * inv);
    }
}

// ---------------- output projection GEMM (f32 out) ----------------

__global__ __launch_bounds__(256) void out_gemm(const u16* __restrict__ A, const u16* __restrict__ Bt,
                                                const float* __restrict__ bias, float* __restrict__ C) {
  __shared__ __align__(16) u16 As[128 * 32];
  __shared__ __align__(16) u16 Bs[128 * 32];
  const int tid = threadIdx.x;
  const int w = tid >> 6, lane = tid & 63, quad = lane >> 4, lc = lane & 15;
  const int K = 1024, N = 1024;
  const int m0 = blockIdx.x * 128, n0 = blockIdx.y * 128;
  const int wrow = (w >> 1) * 64, wcol = (w & 1) * 64;
  const int srow = tid >> 2, sc = tid & 3;
  const u16* Ag = A + (size_t)(m0 + srow) * K + sc * 8;
  const u16* Bg = Bt + (size_t)(n0 + srow) * K + sc * 8;
  u16* Asw = As + w * 512;
  u16* Bsw = Bs + w * 512;

  f32x4 acc[4][4] = {};
  for (int k0 = 0; k0 < K; k0 += 32) {
    async16(Ag + k0, Asw);
    async16(Ag + k0 + (size_t)64 * K, Asw + 2048);
    async16(Bg + k0, Bsw);
    async16(Bg + k0 + (size_t)64 * K, Bsw + 2048);
    __syncthreads();
    bf16x8 af[4], bfr[4];
#pragma unroll
    for (int rt = 0; rt < 4; rt++) af[rt] = *(const bf16x8*)&As[(wrow + rt * 16 + lc) * 32 + quad * 8];
#pragma unroll
    for (int ct = 0; ct < 4; ct++) bfr[ct] = *(const bf16x8*)&Bs[(wcol + ct * 16 + lc) * 32 + quad * 8];
#pragma unroll
    for (int rt = 0; rt < 4; rt++)
#pragma unroll
      for (int ct = 0; ct < 4; ct++)
        acc[rt][ct] = __builtin_amdgcn_mfma_f32_16x16x32_bf16(af[rt], bfr[ct], acc[rt][ct], 0, 0, 0);
    __syncthreads();
  }
#pragma unroll
  for (int ct = 0; ct < 4; ct++) {
    int col = n0 + wcol + ct * 16 + lc;
    float bv = bias[col];
#pragma unroll
    for (int rt = 0; rt < 4; rt++)
#pragma unroll
      for (int r = 0; r < 4; r++) {
        int row = m0 + wrow + rt * 16 + quad * 4 + r;
        C[(size_t)row * N + col] = acc[rt][ct][r] + bv;
      }
  }
}

// ---------------- launcher ----------------

extern "C" void kernel_launch(void* const* d_in, const int* in_sizes, int n_in,
                              void* d_out, int out_size, void* d_ws, size_t ws_size,
                              hipStream_t stream) {
  const int B = 4, S = 2048, D = 1024;
  const float* ctx = (const float*)d_in[0];
  const float* val = (const float*)d_in[1];
  const int*   msk = (const int*)d_in[2];
  const float* Wq  = (const float*)d_in[3];
  const float* bq  = (const float*)d_in[4];
  const float* Wk  = (const float*)d_in[5];
  const float* bk  = (const float*)d_in[6];
  const float* Wv  = (const float*)d_in[7];
  const float* bv  = (const float*)d_in[8];
  const float* Wo  = (const float*)d_in[9];
  const float* bo  = (const float*)d_in[10];
  float* out = (float*)d_out;

  char* ws = (char*)d_ws;
  size_t off = 0;
  auto alloc = [&](size_t sz) { void* p = ws + off; off += (sz + 255) & ~255ULL; return p; };
  const size_t NTOK = (size_t)B * S * D;  // 8388608
  u16* Xc  = (u16*)alloc(NTOK * 2);
  u16* Xv  = (u16*)alloc(NTOK * 2);
  u16* Wqt = (u16*)alloc((size_t)D * D * 2);   // Wqt/Wkt contiguous: fused B matrix
  u16* Wkt = (u16*)alloc((size_t)D * D * 2);
  u16* Wvt = (u16*)alloc((size_t)D * D * 2);
  u16* WoB = (u16*)alloc((size_t)D * D * 2);
  u16* QKb = (u16*)alloc(NTOK * 4);            // fused QK output [B*S][2048]
  u16* Vtg = (u16*)alloc(NTOK * 2);            // V transposed: [bh][dk][S]
  u64* mbits = (u64*)alloc((size_t)S * S / 8); // transposed: [word 0..31][row 0..2047]
  float* bqk = (float*)alloc(2048 * 4);
  u16* AO = Xc;  // alias: Xc dead after QKV GEMM (before attention runs)
  if (off > ws_size) return;  // workspace too small -> visible failure, no OOB

  const float qscale = 0.125f * 1.44269504088896f;  // 1/sqrt(DK) * log2(e)

  prep_kernel<<<34568, 256, 0, stream>>>(ctx, val, msk, Wq, Wk, Wv, Wo, bq, bk,
                                         Xc, Xv, Wqt, Wkt, Wvt, WoB, mbits, bqk);

  // fused Q|K|V projections (QK half N=2048 over Xc; V half N=1024 over Xv, transposed out)
  qkv_gemm<<<dim3(B * S / 128, 24), 256, 0, stream>>>(Xc, Xv, Wqt, Wvt, bqk, bv, QKb, Vtg, qscale);

  // attention
  attn_kernel<<<dim3(S / 128, B * 16), 256, 0, stream>>>(QKb, Vtg, mbits, AO);

  // output projection (f32 out)
  out_gemm<<<dim3(B * S / 128, D / 128), 256, 0, stream>>>(AO, WoB, bo, out);
}